// Round 6
// baseline (247.045 us; speedup 1.0000x reference)
//
#include <hip/hip_runtime.h>
#include <hip/hip_bf16.h>

#define NROW 8192
#define NDIM 128
#define CCHUNK 8  // col tiles per block; grid = (8, 64) -> 512 blocks (R2 sweet spot)

typedef __attribute__((ext_vector_type(8))) short short8;
typedef __attribute__((ext_vector_type(4))) float f32x4;

__device__ __forceinline__ unsigned f2u_mono(float f) {
  unsigned u = __float_as_uint(f);
  return (u & 0x80000000u) ? ~u : (u | 0x80000000u);
}
__device__ __forceinline__ float u2f_mono(unsigned u) {
  return __uint_as_float((u & 0x80000000u) ? (u ^ 0x80000000u) : ~u);
}
__device__ __forceinline__ unsigned short f2bf(float f) {  // RTN fp32->bf16
  unsigned u = __float_as_uint(f);
  u += 0x7fffu + ((u >> 16) & 1u);
  return (unsigned short)(u >> 16);
}

__global__ __launch_bounds__(256) void k_convert(const float* __restrict__ e,
                                                 unsigned short* __restrict__ h) {
  int i = (blockIdx.x * 256 + threadIdx.x) * 8;
  float4 f0 = *reinterpret_cast<const float4*>(e + i);
  float4 f1 = *reinterpret_cast<const float4*>(e + i + 4);
  ushort4 a, b;
  a.x = f2bf(f0.x); a.y = f2bf(f0.y); a.z = f2bf(f0.z); a.w = f2bf(f0.w);
  b.x = f2bf(f1.x); b.y = f2bf(f1.y); b.z = f2bf(f1.z); b.w = f2bf(f1.w);
  *reinterpret_cast<ushort4*>(h + i) = a;
  *reinterpret_cast<ushort4*>(h + i + 4) = b;
}

__device__ __forceinline__ void load_tile(const unsigned short* __restrict__ eh,
                                          const int* __restrict__ labels,
                                          int colBase, int wc, int g, int l15,
                                          short8 (&av)[16], int4 (&lcv)[4]) {
#pragma unroll
  for (int kk = 0; kk < 4; ++kk)
#pragma unroll
    for (int m = 0; m < 4; ++m)
      av[kk * 4 + m] = *reinterpret_cast<const short8*>(
          eh + (size_t)(colBase + wc * 64 + m * 16 + l15) * NDIM + kk * 32 + g * 8);
#pragma unroll
  for (int m = 0; m < 4; ++m)
    lcv[m] = *reinterpret_cast<const int4*>(labels + colBase + wc * 64 + m * 16 + g * 4);
}

__device__ __forceinline__ void mfma_tile(const short8 (&av)[16], const short8 (&bv)[4][4],
                                          f32x4 (&acc)[4][4]) {
#pragma unroll
  for (int m = 0; m < 4; ++m)
#pragma unroll
    for (int n = 0; n < 4; ++n) acc[m][n] = (f32x4){0.f, 0.f, 0.f, 0.f};
#pragma unroll
  for (int kk = 0; kk < 4; ++kk)
#pragma unroll
    for (int m = 0; m < 4; ++m)
#pragma unroll
      for (int n = 0; n < 4; ++n)
        acc[m][n] = __builtin_amdgcn_mfma_f32_16x16x32_bf16(av[kk * 4 + m], bv[kk][n], acc[m][n], 0, 0, 0);
}

// Sparsity-aware epilogue: positives are ~15/8191 per row (512 classes, 8192 rows),
// so per element-group `__any(eq)` is false ~89% of the time -> dense path is
// 1 fmax (PASS1) or fma+exp2+cmp+sel+2add (PASS2). Rare path keeps full logic.
template <int PASS>
__device__ __forceinline__ void epilogue(
    const f32x4 (&acc)[4][4], const int4 (&lcv4)[4],
    int colBase, int rowBase, int wr, int wc, int g, int l15,
    const int (&lr)[4], const float (&thrp)[4], const float (&thrn)[4],
    float (&pminA)[4], float (&nmaxA)[4],
    float (&ap)[4], float (&hp)[4], float (&an)[4], float (&hn)[4]) {
  const bool diagT = (colBase == rowBase);
  int lcv[4][4];
#pragma unroll
  for (int m = 0; m < 4; ++m) {
    lcv[m][0] = lcv4[m].x; lcv[m][1] = lcv4[m].y; lcv[m][2] = lcv4[m].z; lcv[m][3] = lcv4[m].w;
  }
#pragma unroll
  for (int n = 0; n < 4; ++n) {
#pragma unroll
    for (int m = 0; m < 4; ++m) {
#pragma unroll
      for (int r = 0; r < 4; ++r) {
        const float s = acc[m][n][r];
        const bool eq = (lr[n] == lcv[m][r]);
        if (PASS == 1) {
          if (__any(eq)) {  // rare: some lane in this group has a positive
            const bool dg = diagT && (wr == wc) && (m == n) && (l15 == g * 4 + r);
            if (eq && !dg) pminA[n] = fminf(pminA[n], s);
            if (!eq) nmaxA[n] = fmaxf(nmaxA[n], s);
          } else {  // dense: all lanes negative
            nmaxA[n] = fmaxf(nmaxA[n], s);
          }
        } else {
          const float en = exp2f(fmaf(s, 72.13475205f, -36.06737602f));  // exp(50(s-.5))
          if (__any(eq)) {  // rare
            const bool dg = diagT && (wr == wc) && (m == n) && (l15 == g * 4 + r);
            const float ep = exp2f(fmaf(s, -2.885390082f, 1.442695041f));  // exp(-2(s-.5))
            const bool pv = eq && !dg;
            ap[n] += pv ? ep : 0.f;
            hp[n] += (pv && s < thrp[n]) ? ep : 0.f;
            an[n] += eq ? 0.f : en;
            hn[n] += (!eq && s > thrn[n]) ? en : 0.f;
          } else {  // dense: all lanes negative
            an[n] += en;
            hn[n] += (s > thrn[n]) ? en : 0.f;
          }
        }
      }
    }
  }
}

// Column-sweep fused sim GEMM + per-row reductions, LDS-free (E bf16 is L2-resident).
// Pipeline: next tile's fragment loads issue AFTER current MFMA (av_cur dead) so
// they overlap the epilogue without double-buffer spill (peak live ~230 VGPR).
template <int PASS>
__global__ __launch_bounds__(256, 2) void k_sim(
    const unsigned short* __restrict__ eh, const int* __restrict__ labels,
    unsigned* __restrict__ pminu, unsigned* __restrict__ nmaxu,
    float* __restrict__ sums /* [4][NROW]: ap,hp,an,hn */) {
  const int t = threadIdx.x;
  const int lane = t & 63;
  const int wid = t >> 6;
  const int wr = wid >> 1;
  const int wc = wid & 1;
  const int g = lane >> 4;
  const int l15 = lane & 15;
  const int rowBase = blockIdx.y * 128;
  const int col0 = blockIdx.x * CCHUNK * 128;

  // row-operand fragments, registers for the whole sweep
  short8 bv[4][4];  // [kk][n]
  int grow[4], lr[4];
#pragma unroll
  for (int n = 0; n < 4; ++n) {
    grow[n] = rowBase + wr * 64 + n * 16 + l15;
    lr[n] = labels[grow[n]];
#pragma unroll
    for (int kk = 0; kk < 4; ++kk)
      bv[kk][n] = *reinterpret_cast<const short8*>(eh + (size_t)grow[n] * NDIM + kk * 32 + g * 8);
  }

  float pminA[4], nmaxA[4], ap[4], hp[4], an[4], hn[4], thrp[4], thrn[4];
#pragma unroll
  for (int n = 0; n < 4; ++n) {
    pminA[n] = INFINITY; nmaxA[n] = -INFINITY;
    ap[n] = hp[n] = an[n] = hn[n] = 0.f;
    thrp[n] = 0.f; thrn[n] = 0.f;
  }
  if (PASS == 2) {
#pragma unroll
    for (int n = 0; n < 4; ++n) {
      // untouched rows decode to NaN -> all compares false -> hard sums stay 0 (fallback)
      thrp[n] = u2f_mono(nmaxu[grow[n]]) + 0.1f;  // pos_hard: s < neg_max + MARGIN
      thrn[n] = u2f_mono(pminu[grow[n]]) - 0.1f;  // neg_hard: s > pos_min - MARGIN
    }
  }

  short8 avA[16], avB[16];
  int4 lcvA[4], lcvB[4];
  f32x4 acc[4][4];
  load_tile(eh, labels, col0, wc, g, l15, avA, lcvA);

  for (int tp = 0; tp < CCHUNK / 2; ++tp) {  // rolled: bounds code size
    const int c0 = col0 + (2 * tp) * 128;
    const int c1 = c0 + 128;
    mfma_tile(avA, bv, acc);                              // avA dead after this
    load_tile(eh, labels, c1, wc, g, l15, avB, lcvB);     // prefetch under epilogue
    epilogue<PASS>(acc, lcvA, c0, rowBase, wr, wc, g, l15, lr, thrp, thrn,
                   pminA, nmaxA, ap, hp, an, hn);
    mfma_tile(avB, bv, acc);                              // avB dead after this
    if (tp + 1 < CCHUNK / 2)
      load_tile(eh, labels, c1 + 128, wc, g, l15, avA, lcvA);
    epilogue<PASS>(acc, lcvB, c1, rowBase, wr, wc, g, l15, lr, thrp, thrn,
                   pminA, nmaxA, ap, hp, an, hn);
  }

  // block-end combine: butterfly across the 4 g-groups, then one atomic set
#pragma unroll
  for (int n = 0; n < 4; ++n) {
    if (PASS == 1) {
      float pmin = pminA[n], nmax = nmaxA[n];
      pmin = fminf(pmin, __shfl_xor(pmin, 16));
      pmin = fminf(pmin, __shfl_xor(pmin, 32));
      nmax = fmaxf(nmax, __shfl_xor(nmax, 16));
      nmax = fmaxf(nmax, __shfl_xor(nmax, 32));
      if (g == 0 && pmin < INFINITY) atomicMin(&pminu[grow[n]], f2u_mono(pmin));
      if (g == 1 && nmax > -INFINITY) atomicMax(&nmaxu[grow[n]], f2u_mono(nmax));
    } else {
      float a0 = ap[n], a1 = hp[n], a2 = an[n], a3 = hn[n];
      a0 += __shfl_xor(a0, 16); a0 += __shfl_xor(a0, 32);
      a1 += __shfl_xor(a1, 16); a1 += __shfl_xor(a1, 32);
      a2 += __shfl_xor(a2, 16); a2 += __shfl_xor(a2, 32);
      a3 += __shfl_xor(a3, 16); a3 += __shfl_xor(a3, 32);
      float v = (g == 0) ? a0 : (g == 1) ? a1 : (g == 2) ? a2 : a3;
      if (v > 0.f) atomicAdd(sums + g * NROW + grow[n], v);
    }
  }
}

__global__ __launch_bounds__(256) void k_final(const float* __restrict__ sums,
                                               float* __restrict__ out) {
  const int t = threadIdx.x;
  float acc = 0.f, cnt = 0.f;
  for (int i = t; i < NROW; i += 256) {
    float ap = sums[i], hp = sums[NROW + i], an = sums[2 * NROW + i], hn = sums[3 * NROW + i];
    bool valid = (ap > 0.f) && (an > 0.f);
    float ps = (hp > 0.f) ? hp : ap;
    float ns = (hn > 0.f) ? hn : an;
    float loss = 0.5f * log1pf(ps) + 0.02f * log1pf(ns);
    if (valid) { acc += loss; cnt += 1.f; }
  }
#pragma unroll
  for (int o = 32; o > 0; o >>= 1) {
    acc += __shfl_down(acc, o);
    cnt += __shfl_down(cnt, o);
  }
  __shared__ float sa[4], sc[4];
  int w = t >> 6, lane = t & 63;
  if (lane == 0) { sa[w] = acc; sc[w] = cnt; }
  __syncthreads();
  if (t == 0) {
    float A = sa[0] + sa[1] + sa[2] + sa[3];
    float C = sc[0] + sc[1] + sc[2] + sc[3];
    out[0] = A / fmaxf(C, 1.f);
  }
}

extern "C" void kernel_launch(void* const* d_in, const int* in_sizes, int n_in,
                              void* d_out, int out_size, void* d_ws, size_t ws_size,
                              hipStream_t stream) {
  const float* emb = (const float*)d_in[0];
  const int* labels = (const int*)d_in[1];
  float* out = (float*)d_out;

  // ws layout: [bf16 emb: 2MB][pminu:32K][nmaxu:32K][sums: 4x32K]
  unsigned short* embh = (unsigned short*)d_ws;
  unsigned* pminu = (unsigned*)((char*)d_ws + (size_t)NROW * NDIM * 2);
  unsigned* nmaxu = pminu + NROW;
  float* sums = (float*)(nmaxu + NROW);

  hipMemsetAsync(pminu, 0xFF, (size_t)NROW * 4, stream);   // mapped +inf sentinel
  hipMemsetAsync(nmaxu, 0, (size_t)NROW * 4 * 5, stream);  // nmaxu + 4 sums = 0

  k_convert<<<NROW * NDIM / (256 * 8), 256, 0, stream>>>(emb, embh);
  dim3 grid(NROW / 128 / CCHUNK, 64);
  k_sim<1><<<grid, 256, 0, stream>>>(embh, labels, pminu, nmaxu, sums);
  k_sim<2><<<grid, 256, 0, stream>>>(embh, labels, pminu, nmaxu, sums);
  k_final<<<1, 256, 0, stream>>>(sums, out);
}

// Round 7
// 126.251 us; speedup vs baseline: 1.9568x; 1.9568x over previous
//
#include <hip/hip_runtime.h>
#include <hip/hip_bf16.h>

#define NROW 8192
#define NDIM 128
#define CCHUNK 8  // col tiles per block; grid = (8, 64) -> 512 blocks, 2/CU (LDS-capped)

typedef __attribute__((ext_vector_type(8))) short short8;
typedef __attribute__((ext_vector_type(4))) float f32x4;
typedef __attribute__((address_space(1))) const unsigned int guint;
typedef __attribute__((address_space(3))) unsigned int luint;

__device__ __forceinline__ unsigned f2u_mono(float f) {
  unsigned u = __float_as_uint(f);
  return (u & 0x80000000u) ? ~u : (u | 0x80000000u);
}
__device__ __forceinline__ float u2f_mono(unsigned u) {
  return __uint_as_float((u & 0x80000000u) ? (u ^ 0x80000000u) : ~u);
}
__device__ __forceinline__ unsigned short f2bf(float f) {  // RTN fp32->bf16
  unsigned u = __float_as_uint(f);
  u += 0x7fffu + ((u >> 16) & 1u);
  return (unsigned short)(u >> 16);
}

__global__ __launch_bounds__(256) void k_convert(const float* __restrict__ e,
                                                 unsigned short* __restrict__ h) {
  int i = (blockIdx.x * 256 + threadIdx.x) * 8;
  float4 f0 = *reinterpret_cast<const float4*>(e + i);
  float4 f1 = *reinterpret_cast<const float4*>(e + i + 4);
  ushort4 a, b;
  a.x = f2bf(f0.x); a.y = f2bf(f0.y); a.z = f2bf(f0.z); a.w = f2bf(f0.w);
  b.x = f2bf(f1.x); b.y = f2bf(f1.y); b.z = f2bf(f1.z); b.w = f2bf(f1.w);
  *reinterpret_cast<ushort4*>(h + i) = a;
  *reinterpret_cast<ushort4*>(h + i + 4) = b;
}

// DMA one 128x128 bf16 col-tile into LDS. Dest is LINEAR (global_load_lds writes
// wave-uniform base + lane*16); the XOR swizzle is applied to the GLOBAL source
// chunk so that physical LDS slot c of row r holds logical chunk c^(r&7).
__device__ __forceinline__ void stage_tile(const unsigned short* __restrict__ eh,
                                           int colBase, int t,
                                           unsigned short* __restrict__ Lbuf) {
#pragma unroll
  for (int it = 0; it < 8; ++it) {
    const int r = it * 16 + (t >> 4);   // 0..127
    const int c = t & 15;               // physical 16B slot
    const int q = c ^ (r & 7);          // logical source chunk
    const unsigned short* src = eh + (size_t)(colBase + r) * NDIM + q * 8;
    unsigned short* dst = Lbuf + r * NDIM + c * 8;  // = wave base + lane*16
    __builtin_amdgcn_global_load_lds((guint*)src, (luint*)dst, 16, 0, 0);
  }
}

// Fragment reads from LDS with the matching XOR: logical chunk kk*4+g of row R
// lives at physical chunk (kk*4+g)^(R&7). Spreads the 64 lanes across all 32 banks.
__device__ __forceinline__ void mfma_from_lds(const unsigned short* __restrict__ Lbuf,
                                              const short8 (&bv)[4][4],
                                              int wc, int g, int l15,
                                              f32x4 (&acc)[4][4]) {
#pragma unroll
  for (int m = 0; m < 4; ++m)
#pragma unroll
    for (int n = 0; n < 4; ++n) acc[m][n] = (f32x4){0.f, 0.f, 0.f, 0.f};
#pragma unroll
  for (int kk = 0; kk < 4; ++kk) {
    short8 av[4];
#pragma unroll
    for (int m = 0; m < 4; ++m) {
      const int R = wc * 64 + m * 16 + l15;
      const int pc = (kk * 4 + g) ^ (R & 7);
      av[m] = *reinterpret_cast<const short8*>(Lbuf + R * NDIM + pc * 8);
    }
#pragma unroll
    for (int m = 0; m < 4; ++m)
#pragma unroll
      for (int n = 0; n < 4; ++n)
        acc[m][n] = __builtin_amdgcn_mfma_f32_16x16x32_bf16(av[m], bv[kk][n], acc[m][n], 0, 0, 0);
  }
}

// Sparsity-aware epilogue: positives ~16/8192 per row -> __any(eq) false for ~89%
// of element-groups; dense path = 1 fmax (PASS1) or fma+exp2+cmp+sel+2add (PASS2).
template <int PASS>
__device__ __forceinline__ void epilogue(
    const f32x4 (&acc)[4][4], const int4 (&lcv4)[4],
    int colBase, int rowBase, int wr, int wc, int g, int l15,
    const int (&lr)[4], const float (&thrp)[4], const float (&thrn)[4],
    float (&pminA)[4], float (&nmaxA)[4],
    float (&ap)[4], float (&hp)[4], float (&an)[4], float (&hn)[4]) {
  const bool diagT = (colBase == rowBase);
  int lcv[4][4];
#pragma unroll
  for (int m = 0; m < 4; ++m) {
    lcv[m][0] = lcv4[m].x; lcv[m][1] = lcv4[m].y; lcv[m][2] = lcv4[m].z; lcv[m][3] = lcv4[m].w;
  }
#pragma unroll
  for (int n = 0; n < 4; ++n) {
#pragma unroll
    for (int m = 0; m < 4; ++m) {
#pragma unroll
      for (int r = 0; r < 4; ++r) {
        const float s = acc[m][n][r];
        const bool eq = (lr[n] == lcv[m][r]);
        if (PASS == 1) {
          if (__any(eq)) {
            const bool dg = diagT && (wr == wc) && (m == n) && (l15 == g * 4 + r);
            if (eq && !dg) pminA[n] = fminf(pminA[n], s);
            if (!eq) nmaxA[n] = fmaxf(nmaxA[n], s);
          } else {
            nmaxA[n] = fmaxf(nmaxA[n], s);
          }
        } else {
          const float en = exp2f(fmaf(s, 72.13475205f, -36.06737602f));  // exp(50(s-.5))
          if (__any(eq)) {
            const bool dg = diagT && (wr == wc) && (m == n) && (l15 == g * 4 + r);
            const float ep = exp2f(fmaf(s, -2.885390082f, 1.442695041f));  // exp(-2(s-.5))
            const bool pv = eq && !dg;
            ap[n] += pv ? ep : 0.f;
            hp[n] += (pv && s < thrp[n]) ? ep : 0.f;
            an[n] += eq ? 0.f : en;
            hn[n] += (!eq && s > thrn[n]) ? en : 0.f;
          } else {
            an[n] += en;
            hn[n] += (s > thrn[n]) ? en : 0.f;
          }
        }
      }
    }
  }
}

// Column-sweep fused sim GEMM + per-row reductions. Col tiles double-buffered in
// LDS via global_load_lds DMA (zero VGPR cost for in-flight data); row fragments
// + all reduction state in registers for the whole sweep; one atomic set/block.
template <int PASS>
__global__ __launch_bounds__(256, 2) void k_sim(
    const unsigned short* __restrict__ eh, const int* __restrict__ labels,
    unsigned* __restrict__ pminu, unsigned* __restrict__ nmaxu,
    float* __restrict__ sums /* [4][NROW]: ap,hp,an,hn */) {
  __shared__ unsigned short L[2][128 * NDIM];  // 2 x 32KB

  const int t = threadIdx.x;
  const int lane = t & 63;
  const int wid = t >> 6;
  const int wr = wid >> 1;
  const int wc = wid & 1;
  const int g = lane >> 4;
  const int l15 = lane & 15;
  const int rowBase = blockIdx.y * 128;
  const int col0 = blockIdx.x * CCHUNK * 128;

  stage_tile(eh, col0, t, L[0]);  // prologue DMA for tile 0

  // row-operand fragments, registers for the whole sweep
  short8 bv[4][4];  // [kk][n]
  int grow[4], lr[4];
#pragma unroll
  for (int n = 0; n < 4; ++n) {
    grow[n] = rowBase + wr * 64 + n * 16 + l15;
    lr[n] = labels[grow[n]];
#pragma unroll
    for (int kk = 0; kk < 4; ++kk)
      bv[kk][n] = *reinterpret_cast<const short8*>(eh + (size_t)grow[n] * NDIM + kk * 32 + g * 8);
  }

  float pminA[4], nmaxA[4], ap[4], hp[4], an[4], hn[4], thrp[4], thrn[4];
#pragma unroll
  for (int n = 0; n < 4; ++n) {
    pminA[n] = INFINITY; nmaxA[n] = -INFINITY;
    ap[n] = hp[n] = an[n] = hn[n] = 0.f;
    thrp[n] = 0.f; thrn[n] = 0.f;
  }
  if (PASS == 2) {
#pragma unroll
    for (int n = 0; n < 4; ++n) {
      // untouched rows decode to NaN -> all compares false -> hard sums stay 0 (fallback)
      thrp[n] = u2f_mono(nmaxu[grow[n]]) + 0.1f;  // pos_hard: s < neg_max + MARGIN
      thrn[n] = u2f_mono(pminu[grow[n]]) - 0.1f;  // neg_hard: s > pos_min - MARGIN
    }
  }

  asm volatile("s_waitcnt vmcnt(0)");  // tile-0 DMA (and bv loads) landed
  __syncthreads();

  f32x4 acc[4][4];
  int cur = 0;
  for (int tt = 0; tt < CCHUNK; ++tt) {
    const int colBase = col0 + tt * 128;
    if (tt + 1 < CCHUNK) stage_tile(eh, colBase + 128, t, L[cur ^ 1]);  // DMA next
    mfma_from_lds(L[cur], bv, wc, g, l15, acc);
    int4 lcv4[4];
#pragma unroll
    for (int m = 0; m < 4; ++m)
      lcv4[m] = *reinterpret_cast<const int4*>(labels + colBase + wc * 64 + m * 16 + g * 4);
    epilogue<PASS>(acc, lcv4, colBase, rowBase, wr, wc, g, l15, lr, thrp, thrn,
                   pminA, nmaxA, ap, hp, an, hn);
    asm volatile("s_waitcnt vmcnt(0)");  // next-tile DMA landed (covered by compute)
    __syncthreads();
    cur ^= 1;
  }

  // block-end combine: butterfly across the 4 g-groups, then one atomic set
#pragma unroll
  for (int n = 0; n < 4; ++n) {
    if (PASS == 1) {
      float pmin = pminA[n], nmax = nmaxA[n];
      pmin = fminf(pmin, __shfl_xor(pmin, 16));
      pmin = fminf(pmin, __shfl_xor(pmin, 32));
      nmax = fmaxf(nmax, __shfl_xor(nmax, 16));
      nmax = fmaxf(nmax, __shfl_xor(nmax, 32));
      if (g == 0 && pmin < INFINITY) atomicMin(&pminu[grow[n]], f2u_mono(pmin));
      if (g == 1 && nmax > -INFINITY) atomicMax(&nmaxu[grow[n]], f2u_mono(nmax));
    } else {
      float a0 = ap[n], a1 = hp[n], a2 = an[n], a3 = hn[n];
      a0 += __shfl_xor(a0, 16); a0 += __shfl_xor(a0, 32);
      a1 += __shfl_xor(a1, 16); a1 += __shfl_xor(a1, 32);
      a2 += __shfl_xor(a2, 16); a2 += __shfl_xor(a2, 32);
      a3 += __shfl_xor(a3, 16); a3 += __shfl_xor(a3, 32);
      float v = (g == 0) ? a0 : (g == 1) ? a1 : (g == 2) ? a2 : a3;
      if (v > 0.f) atomicAdd(sums + g * NROW + grow[n], v);
    }
  }
}

__global__ __launch_bounds__(256) void k_final(const float* __restrict__ sums,
                                               float* __restrict__ out) {
  const int t = threadIdx.x;
  float acc = 0.f, cnt = 0.f;
  for (int i = t; i < NROW; i += 256) {
    float ap = sums[i], hp = sums[NROW + i], an = sums[2 * NROW + i], hn = sums[3 * NROW + i];
    bool valid = (ap > 0.f) && (an > 0.f);
    float ps = (hp > 0.f) ? hp : ap;
    float ns = (hn > 0.f) ? hn : an;
    float loss = 0.5f * log1pf(ps) + 0.02f * log1pf(ns);
    if (valid) { acc += loss; cnt += 1.f; }
  }
#pragma unroll
  for (int o = 32; o > 0; o >>= 1) {
    acc += __shfl_down(acc, o);
    cnt += __shfl_down(cnt, o);
  }
  __shared__ float sa[4], sc[4];
  int w = t >> 6, lane = t & 63;
  if (lane == 0) { sa[w] = acc; sc[w] = cnt; }
  __syncthreads();
  if (t == 0) {
    float A = sa[0] + sa[1] + sa[2] + sa[3];
    float C = sc[0] + sc[1] + sc[2] + sc[3];
    out[0] = A / fmaxf(C, 1.f);
  }
}

extern "C" void kernel_launch(void* const* d_in, const int* in_sizes, int n_in,
                              void* d_out, int out_size, void* d_ws, size_t ws_size,
                              hipStream_t stream) {
  const float* emb = (const float*)d_in[0];
  const int* labels = (const int*)d_in[1];
  float* out = (float*)d_out;

  // ws layout: [bf16 emb: 2MB][pminu:32K][nmaxu:32K][sums: 4x32K]
  unsigned short* embh = (unsigned short*)d_ws;
  unsigned* pminu = (unsigned*)((char*)d_ws + (size_t)NROW * NDIM * 2);
  unsigned* nmaxu = pminu + NROW;
  float* sums = (float*)(nmaxu + NROW);

  hipMemsetAsync(pminu, 0xFF, (size_t)NROW * 4, stream);   // mapped +inf sentinel
  hipMemsetAsync(nmaxu, 0, (size_t)NROW * 4 * 5, stream);  // nmaxu + 4 sums = 0

  k_convert<<<NROW * NDIM / (256 * 8), 256, 0, stream>>>(emb, embh);
  dim3 grid(NROW / 128 / CCHUNK, 64);
  k_sim<1><<<grid, 256, 0, stream>>>(embh, labels, pminu, nmaxu, sums);
  k_sim<2><<<grid, 256, 0, stream>>>(embh, labels, pminu, nmaxu, sums);
  k_final<<<1, 256, 0, stream>>>(sums, out);
}

// Round 8
// 111.079 us; speedup vs baseline: 2.2240x; 1.1366x over previous
//
#include <hip/hip_runtime.h>
#include <hip/hip_bf16.h>

#define NROW 8192
#define NDIM 128
#define CTILE 64  // cols per tile (16KB LDS) -> L[2]=32KB/block -> 3-4 blocks/CU
#define CCHUNK 8  // tiles per block -> 512 cols/block; grid (16,64)=1024 blocks

typedef __attribute__((ext_vector_type(8))) short short8;
typedef __attribute__((ext_vector_type(4))) float f32x4;
typedef __attribute__((address_space(1))) const unsigned int guint;
typedef __attribute__((address_space(3))) unsigned int luint;

__device__ __forceinline__ unsigned f2u_mono(float f) {
  unsigned u = __float_as_uint(f);
  return (u & 0x80000000u) ? ~u : (u | 0x80000000u);
}
__device__ __forceinline__ float u2f_mono(unsigned u) {
  return __uint_as_float((u & 0x80000000u) ? (u ^ 0x80000000u) : ~u);
}
__device__ __forceinline__ unsigned short f2bf(float f) {  // RTN fp32->bf16
  unsigned u = __float_as_uint(f);
  u += 0x7fffu + ((u >> 16) & 1u);
  return (unsigned short)(u >> 16);
}

__global__ __launch_bounds__(256) void k_convert(const float* __restrict__ e,
                                                 unsigned short* __restrict__ h) {
  int i = (blockIdx.x * 256 + threadIdx.x) * 8;
  float4 f0 = *reinterpret_cast<const float4*>(e + i);
  float4 f1 = *reinterpret_cast<const float4*>(e + i + 4);
  ushort4 a, b;
  a.x = f2bf(f0.x); a.y = f2bf(f0.y); a.z = f2bf(f0.z); a.w = f2bf(f0.w);
  b.x = f2bf(f1.x); b.y = f2bf(f1.y); b.z = f2bf(f1.z); b.w = f2bf(f1.w);
  *reinterpret_cast<ushort4*>(h + i) = a;
  *reinterpret_cast<ushort4*>(h + i + 4) = b;
}

// DMA one 64x128 bf16 col-tile into LDS. Dest LINEAR (global_load_lds writes
// wave-uniform base + lane*16); XOR swizzle applied to the GLOBAL source chunk:
// physical slot c of row r holds logical chunk c^(r&15).
__device__ __forceinline__ void stage_tile(const unsigned short* __restrict__ eh,
                                           int colBase, int t,
                                           unsigned short* __restrict__ Lbuf) {
#pragma unroll
  for (int it = 0; it < 4; ++it) {
    const int idx = it * 256 + t;
    const int r = idx >> 4;             // 0..63
    const int c = idx & 15;             // physical 16B slot
    const int q = c ^ (r & 15);         // logical source chunk
    const unsigned short* src = eh + (size_t)(colBase + r) * NDIM + q * 8;
    unsigned short* dst = Lbuf + r * NDIM + c * 8;
    __builtin_amdgcn_global_load_lds((guint*)src, (luint*)dst, 16, 0, 0);
  }
}

// Fragment reads with matching XOR: logical chunk kk*4+g of row R at physical
// chunk (kk*4+g)^(R&15); R&15 == l15 here -> 16 distinct chunks per lane group.
__device__ __forceinline__ void mfma_from_lds(const unsigned short* __restrict__ Lbuf,
                                              const short8 (&bv)[4][2],
                                              int g, int l15,
                                              f32x4 (&acc)[4][2]) {
#pragma unroll
  for (int m = 0; m < 4; ++m)
#pragma unroll
    for (int n = 0; n < 2; ++n) acc[m][n] = (f32x4){0.f, 0.f, 0.f, 0.f};
#pragma unroll
  for (int kk = 0; kk < 4; ++kk) {
    short8 av[4];
#pragma unroll
    for (int m = 0; m < 4; ++m) {
      const int R = m * 16 + l15;
      const int pc = (kk * 4 + g) ^ l15;
      av[m] = *reinterpret_cast<const short8*>(Lbuf + R * NDIM + pc * 8);
    }
#pragma unroll
    for (int m = 0; m < 4; ++m)
#pragma unroll
      for (int n = 0; n < 2; ++n)
        acc[m][n] = __builtin_amdgcn_mfma_f32_16x16x32_bf16(av[m], bv[kk][n], acc[m][n], 0, 0, 0);
  }
}

// Branchless epilogues (no per-group branches — they cost more than they save).
// PASS2 single-exp: coefficients selected by eq, hard-mining compare unified by
// sign flip (neg thresh pre-negated). NaN sentinels keep hard sums 0 (fallback).
template <int PASS, bool DIAG>
__device__ __forceinline__ void epilogue(
    const f32x4 (&acc)[4][2], const int (&lcv)[4][4],
    int colBase, int rowBase, int wid, int g, int l15,
    const int (&lr)[2], const float (&thrp)[2], const float (&nthrn)[2],
    float (&pminA)[2], float (&nmaxA)[2],
    float (&ap)[2], float (&hp)[2], float (&an)[2], float (&hn)[2]) {
#pragma unroll
  for (int n = 0; n < 2; ++n) {
    const int grow = rowBase + wid * 32 + n * 16 + l15;
#pragma unroll
    for (int m = 0; m < 4; ++m) {
#pragma unroll
      for (int r = 0; r < 4; ++r) {
        const float s = acc[m][n][r];
        const bool eq = (lr[n] == lcv[m][r]);
        bool pv = eq;
        if (DIAG) {
          const bool dg = (grow == colBase + m * 16 + g * 4 + r);
          pv = eq && !dg;
        }
        if (PASS == 1) {
          pminA[n] = fminf(pminA[n], pv ? s : INFINITY);
          nmaxA[n] = fmaxf(nmaxA[n], eq ? -INFINITY : s);
        } else {
          const float cA = eq ? -2.885390082f : 72.13475205f;   // -2/ln2 : 50/ln2
          const float cB = eq ? 1.442695041f : -36.06737602f;   //  1/ln2 : -25/ln2
          const float e = exp2f(fmaf(s, cA, cB));
          const float sS = eq ? s : -s;
          const float tS = eq ? thrp[n] : nthrn[n];
          const bool hard = sS < tS;
          ap[n] += pv ? e : 0.f;
          hp[n] += (pv && hard) ? e : 0.f;
          an[n] += eq ? 0.f : e;
          hn[n] += (!eq && hard) ? e : 0.f;
        }
      }
    }
  }
}

// Column-sweep fused sim GEMM + per-row reductions. 64-col tiles double-buffered
// in LDS (32KB/block -> 3-4 blocks/CU, 12-16 waves/CU). Row fragments + reduction
// state in registers for the whole sweep; one atomic set per block.
template <int PASS>
__global__ __launch_bounds__(256, 3) void k_sim(
    const unsigned short* __restrict__ eh, const int* __restrict__ labels,
    unsigned* __restrict__ pminu, unsigned* __restrict__ nmaxu,
    float* __restrict__ sums /* [4][NROW]: ap,hp,an,hn */) {
  __shared__ unsigned short L[2][CTILE * NDIM];  // 2 x 16KB

  const int t = threadIdx.x;
  const int lane = t & 63;
  const int wid = t >> 6;   // 4-way row split: wave owns 32 rows
  const int g = lane >> 4;
  const int l15 = lane & 15;
  const int rowBase = blockIdx.y * 128;
  const int col0 = blockIdx.x * CCHUNK * CTILE;

  stage_tile(eh, col0, t, L[0]);  // prologue DMA for tile 0

  // row-operand fragments (rows wid*32 .. wid*32+31), registers for whole sweep
  short8 bv[4][2];  // [kk][n]
  int lr[2];
#pragma unroll
  for (int n = 0; n < 2; ++n) {
    const int grow = rowBase + wid * 32 + n * 16 + l15;
    lr[n] = labels[grow];
#pragma unroll
    for (int kk = 0; kk < 4; ++kk)
      bv[kk][n] = *reinterpret_cast<const short8*>(eh + (size_t)grow * NDIM + kk * 32 + g * 8);
  }

  float pminA[2], nmaxA[2], ap[2], hp[2], an[2], hn[2], thrp[2], nthrn[2];
#pragma unroll
  for (int n = 0; n < 2; ++n) {
    pminA[n] = INFINITY; nmaxA[n] = -INFINITY;
    ap[n] = hp[n] = an[n] = hn[n] = 0.f;
    thrp[n] = 0.f; nthrn[n] = 0.f;
  }
  if (PASS == 2) {
#pragma unroll
    for (int n = 0; n < 2; ++n) {
      const int grow = rowBase + wid * 32 + n * 16 + l15;
      // untouched rows decode to NaN -> compares false -> hard sums stay 0 (fallback)
      thrp[n] = u2f_mono(nmaxu[grow]) + 0.1f;         // pos_hard: s < neg_max + M
      nthrn[n] = 0.1f - u2f_mono(pminu[grow]);        // neg_hard: -s < -(pos_min - M)
    }
  }

  asm volatile("s_waitcnt vmcnt(0)");
  __syncthreads();

  f32x4 acc[4][2];
  int cur = 0;
  for (int tt = 0; tt < CCHUNK; ++tt) {
    const int colBase = col0 + tt * CTILE;
    if (tt + 1 < CCHUNK) stage_tile(eh, colBase + CTILE, t, L[cur ^ 1]);  // DMA next
    mfma_from_lds(L[cur], bv, g, l15, acc);
    int lcv[4][4];
#pragma unroll
    for (int m = 0; m < 4; ++m) {
      int4 lv = *reinterpret_cast<const int4*>(labels + colBase + m * 16 + g * 4);
      lcv[m][0] = lv.x; lcv[m][1] = lv.y; lcv[m][2] = lv.z; lcv[m][3] = lv.w;
    }
    if ((unsigned)(colBase - rowBase) < 128u)  // tile touches the diagonal
      epilogue<PASS, true>(acc, lcv, colBase, rowBase, wid, g, l15, lr, thrp, nthrn,
                           pminA, nmaxA, ap, hp, an, hn);
    else
      epilogue<PASS, false>(acc, lcv, colBase, rowBase, wid, g, l15, lr, thrp, nthrn,
                            pminA, nmaxA, ap, hp, an, hn);
    asm volatile("s_waitcnt vmcnt(0)");  // next-tile DMA landed (covered by compute)
    __syncthreads();
    cur ^= 1;
  }

  // block-end combine: butterfly across the 4 g-groups, then one atomic set
#pragma unroll
  for (int n = 0; n < 2; ++n) {
    const int grow = rowBase + wid * 32 + n * 16 + l15;
    if (PASS == 1) {
      float pmin = pminA[n], nmax = nmaxA[n];
      pmin = fminf(pmin, __shfl_xor(pmin, 16));
      pmin = fminf(pmin, __shfl_xor(pmin, 32));
      nmax = fmaxf(nmax, __shfl_xor(nmax, 16));
      nmax = fmaxf(nmax, __shfl_xor(nmax, 32));
      if (g == 0 && pmin < INFINITY) atomicMin(&pminu[grow], f2u_mono(pmin));
      if (g == 1 && nmax > -INFINITY) atomicMax(&nmaxu[grow], f2u_mono(nmax));
    } else {
      float a0 = ap[n], a1 = hp[n], a2 = an[n], a3 = hn[n];
      a0 += __shfl_xor(a0, 16); a0 += __shfl_xor(a0, 32);
      a1 += __shfl_xor(a1, 16); a1 += __shfl_xor(a1, 32);
      a2 += __shfl_xor(a2, 16); a2 += __shfl_xor(a2, 32);
      a3 += __shfl_xor(a3, 16); a3 += __shfl_xor(a3, 32);
      float v = (g == 0) ? a0 : (g == 1) ? a1 : (g == 2) ? a2 : a3;
      if (v > 0.f) atomicAdd(sums + g * NROW + grow, v);
    }
  }
}

__global__ __launch_bounds__(256) void k_final(const float* __restrict__ sums,
                                               float* __restrict__ out) {
  const int t = threadIdx.x;
  float acc = 0.f, cnt = 0.f;
  for (int i = t; i < NROW; i += 256) {
    float ap = sums[i], hp = sums[NROW + i], an = sums[2 * NROW + i], hn = sums[3 * NROW + i];
    bool valid = (ap > 0.f) && (an > 0.f);
    float ps = (hp > 0.f) ? hp : ap;
    float ns = (hn > 0.f) ? hn : an;
    float loss = 0.5f * log1pf(ps) + 0.02f * log1pf(ns);
    if (valid) { acc += loss; cnt += 1.f; }
  }
#pragma unroll
  for (int o = 32; o > 0; o >>= 1) {
    acc += __shfl_down(acc, o);
    cnt += __shfl_down(cnt, o);
  }
  __shared__ float sa[4], sc[4];
  int w = t >> 6, lane = t & 63;
  if (lane == 0) { sa[w] = acc; sc[w] = cnt; }
  __syncthreads();
  if (t == 0) {
    float A = sa[0] + sa[1] + sa[2] + sa[3];
    float C = sc[0] + sc[1] + sc[2] + sc[3];
    out[0] = A / fmaxf(C, 1.f);
  }
}

extern "C" void kernel_launch(void* const* d_in, const int* in_sizes, int n_in,
                              void* d_out, int out_size, void* d_ws, size_t ws_size,
                              hipStream_t stream) {
  const float* emb = (const float*)d_in[0];
  const int* labels = (const int*)d_in[1];
  float* out = (float*)d_out;

  // ws layout: [bf16 emb: 2MB][pminu:32K][nmaxu:32K][sums: 4x32K]
  unsigned short* embh = (unsigned short*)d_ws;
  unsigned* pminu = (unsigned*)((char*)d_ws + (size_t)NROW * NDIM * 2);
  unsigned* nmaxu = pminu + NROW;
  float* sums = (float*)(nmaxu + NROW);

  hipMemsetAsync(pminu, 0xFF, (size_t)NROW * 4, stream);   // mapped +inf sentinel
  hipMemsetAsync(nmaxu, 0, (size_t)NROW * 4 * 5, stream);  // nmaxu + 4 sums = 0

  k_convert<<<NROW * NDIM / (256 * 8), 256, 0, stream>>>(emb, embh);
  dim3 grid(NROW / (CTILE * CCHUNK), 64);
  k_sim<1><<<grid, 256, 0, stream>>>(embh, labels, pminu, nmaxu, sums);
  k_sim<2><<<grid, 256, 0, stream>>>(embh, labels, pminu, nmaxu, sums);
  k_final<<<1, 256, 0, stream>>>(sums, out);
}

// Round 9
// 111.010 us; speedup vs baseline: 2.2254x; 1.0006x over previous
//
#include <hip/hip_runtime.h>
#include <hip/hip_bf16.h>

#define NROW 8192
#define NDIM 128
#define CTILE 64  // cols per tile (16KB LDS) -> L[2]=32KB/block -> 3-4 blocks/CU
#define CCHUNK 8  // tiles per block -> 512 cols/block; grid (16,64)=1024 blocks

typedef __attribute__((ext_vector_type(8))) short short8;
typedef __attribute__((ext_vector_type(4))) float f32x4;
typedef __attribute__((address_space(1))) const unsigned int guint;
typedef __attribute__((address_space(3))) unsigned int luint;

__device__ __forceinline__ unsigned f2u_mono(float f) {
  unsigned u = __float_as_uint(f);
  return (u & 0x80000000u) ? ~u : (u | 0x80000000u);
}
__device__ __forceinline__ float u2f_mono(unsigned u) {
  return __uint_as_float((u & 0x80000000u) ? (u ^ 0x80000000u) : ~u);
}
__device__ __forceinline__ unsigned short f2bf(float f) {  // RTN fp32->bf16
  unsigned u = __float_as_uint(f);
  u += 0x7fffu + ((u >> 16) & 1u);
  return (unsigned short)(u >> 16);
}

__global__ __launch_bounds__(256) void k_convert(const float* __restrict__ e,
                                                 unsigned short* __restrict__ h) {
  int i = (blockIdx.x * 256 + threadIdx.x) * 8;
  float4 f0 = *reinterpret_cast<const float4*>(e + i);
  float4 f1 = *reinterpret_cast<const float4*>(e + i + 4);
  ushort4 a, b;
  a.x = f2bf(f0.x); a.y = f2bf(f0.y); a.z = f2bf(f0.z); a.w = f2bf(f0.w);
  b.x = f2bf(f1.x); b.y = f2bf(f1.y); b.z = f2bf(f1.z); b.w = f2bf(f1.w);
  *reinterpret_cast<ushort4*>(h + i) = a;
  *reinterpret_cast<ushort4*>(h + i + 4) = b;
}

// DMA one 64x128 bf16 col-tile into LDS. Dest LINEAR (global_load_lds writes
// wave-uniform base + lane*16); XOR swizzle applied to the GLOBAL source chunk:
// physical slot c of row r holds logical chunk c^(r&15).
__device__ __forceinline__ void stage_tile(const unsigned short* __restrict__ eh,
                                           int colBase, int t,
                                           unsigned short* __restrict__ Lbuf) {
#pragma unroll
  for (int it = 0; it < 4; ++it) {
    const int idx = it * 256 + t;
    const int r = idx >> 4;             // 0..63
    const int c = idx & 15;             // physical 16B slot
    const int q = c ^ (r & 15);         // logical source chunk
    const unsigned short* src = eh + (size_t)(colBase + r) * NDIM + q * 8;
    unsigned short* dst = Lbuf + r * NDIM + c * 8;
    __builtin_amdgcn_global_load_lds((guint*)src, (luint*)dst, 16, 0, 0);
  }
}

// Fragment reads with matching XOR: logical chunk kk*4+g of row R at physical
// chunk (kk*4+g)^(R&15); R&15 == l15 here -> 16 distinct chunks per lane group.
__device__ __forceinline__ void mfma_from_lds(const unsigned short* __restrict__ Lbuf,
                                              const short8 (&bv)[4][2],
                                              int g, int l15,
                                              f32x4 (&acc)[4][2]) {
#pragma unroll
  for (int m = 0; m < 4; ++m)
#pragma unroll
    for (int n = 0; n < 2; ++n) acc[m][n] = (f32x4){0.f, 0.f, 0.f, 0.f};
#pragma unroll
  for (int kk = 0; kk < 4; ++kk) {
    short8 av[4];
#pragma unroll
    for (int m = 0; m < 4; ++m) {
      const int R = m * 16 + l15;
      const int pc = (kk * 4 + g) ^ l15;
      av[m] = *reinterpret_cast<const short8*>(Lbuf + R * NDIM + pc * 8);
    }
#pragma unroll
    for (int m = 0; m < 4; ++m)
#pragma unroll
      for (int n = 0; n < 2; ++n)
        acc[m][n] = __builtin_amdgcn_mfma_f32_16x16x32_bf16(av[m], bv[kk][n], acc[m][n], 0, 0, 0);
  }
}

// Branchless epilogues (no per-group branches — they cost more than they save).
// PASS2 single-exp: coefficients selected by eq, hard-mining compare unified by
// sign flip (neg thresh pre-negated). NaN sentinels keep hard sums 0 (fallback).
template <int PASS, bool DIAG>
__device__ __forceinline__ void epilogue(
    const f32x4 (&acc)[4][2], const int (&lcv)[4][4],
    int colBase, int rowBase, int wid, int g, int l15,
    const int (&lr)[2], const float (&thrp)[2], const float (&nthrn)[2],
    float (&pminA)[2], float (&nmaxA)[2],
    float (&ap)[2], float (&hp)[2], float (&an)[2], float (&hn)[2]) {
#pragma unroll
  for (int n = 0; n < 2; ++n) {
    const int grow = rowBase + wid * 32 + n * 16 + l15;
#pragma unroll
    for (int m = 0; m < 4; ++m) {
#pragma unroll
      for (int r = 0; r < 4; ++r) {
        const float s = acc[m][n][r];
        const bool eq = (lr[n] == lcv[m][r]);
        bool pv = eq;
        if (DIAG) {
          const bool dg = (grow == colBase + m * 16 + g * 4 + r);
          pv = eq && !dg;
        }
        if (PASS == 1) {
          pminA[n] = fminf(pminA[n], pv ? s : INFINITY);
          nmaxA[n] = fmaxf(nmaxA[n], eq ? -INFINITY : s);
        } else {
          const float cA = eq ? -2.885390082f : 72.13475205f;   // -2/ln2 : 50/ln2
          const float cB = eq ? 1.442695041f : -36.06737602f;   //  1/ln2 : -25/ln2
          const float e = exp2f(fmaf(s, cA, cB));
          const float sS = eq ? s : -s;
          const float tS = eq ? thrp[n] : nthrn[n];
          const bool hard = sS < tS;
          ap[n] += pv ? e : 0.f;
          hp[n] += (pv && hard) ? e : 0.f;
          an[n] += eq ? 0.f : e;
          hn[n] += (!eq && hard) ? e : 0.f;
        }
      }
    }
  }
}

// Column-sweep fused sim GEMM + per-row reductions. 64-col tiles double-buffered
// in LDS (32KB/block -> 3-4 blocks/CU, 12-16 waves/CU). Row fragments + reduction
// state in registers for the whole sweep; one atomic set per block.
template <int PASS>
__global__ __launch_bounds__(256, 3) void k_sim(
    const unsigned short* __restrict__ eh, const int* __restrict__ labels,
    unsigned* __restrict__ pminu, unsigned* __restrict__ nmaxu,
    float* __restrict__ sums /* [4][NROW]: ap,hp,an,hn */) {
  __shared__ unsigned short L[2][CTILE * NDIM];  // 2 x 16KB

  const int t = threadIdx.x;
  const int lane = t & 63;
  const int wid = t >> 6;   // 4-way row split: wave owns 32 rows
  const int g = lane >> 4;
  const int l15 = lane & 15;
  const int rowBase = blockIdx.y * 128;
  const int col0 = blockIdx.x * CCHUNK * CTILE;

  stage_tile(eh, col0, t, L[0]);  // prologue DMA for tile 0

  // row-operand fragments (rows wid*32 .. wid*32+31), registers for whole sweep
  short8 bv[4][2];  // [kk][n]
  int lr[2];
#pragma unroll
  for (int n = 0; n < 2; ++n) {
    const int grow = rowBase + wid * 32 + n * 16 + l15;
    lr[n] = labels[grow];
#pragma unroll
    for (int kk = 0; kk < 4; ++kk)
      bv[kk][n] = *reinterpret_cast<const short8*>(eh + (size_t)grow * NDIM + kk * 32 + g * 8);
  }

  float pminA[2], nmaxA[2], ap[2], hp[2], an[2], hn[2], thrp[2], nthrn[2];
#pragma unroll
  for (int n = 0; n < 2; ++n) {
    pminA[n] = INFINITY; nmaxA[n] = -INFINITY;
    ap[n] = hp[n] = an[n] = hn[n] = 0.f;
    thrp[n] = 0.f; nthrn[n] = 0.f;
  }
  if (PASS == 2) {
#pragma unroll
    for (int n = 0; n < 2; ++n) {
      const int grow = rowBase + wid * 32 + n * 16 + l15;
      // untouched rows decode to NaN -> compares false -> hard sums stay 0 (fallback)
      thrp[n] = u2f_mono(nmaxu[grow]) + 0.1f;         // pos_hard: s < neg_max + M
      nthrn[n] = 0.1f - u2f_mono(pminu[grow]);        // neg_hard: -s < -(pos_min - M)
    }
  }

  asm volatile("s_waitcnt vmcnt(0)");
  __syncthreads();

  f32x4 acc[4][2];
  int cur = 0;
  for (int tt = 0; tt < CCHUNK; ++tt) {
    const int colBase = col0 + tt * CTILE;
    if (tt + 1 < CCHUNK) stage_tile(eh, colBase + CTILE, t, L[cur ^ 1]);  // DMA next
    mfma_from_lds(L[cur], bv, g, l15, acc);
    int lcv[4][4];
#pragma unroll
    for (int m = 0; m < 4; ++m) {
      int4 lv = *reinterpret_cast<const int4*>(labels + colBase + m * 16 + g * 4);
      lcv[m][0] = lv.x; lcv[m][1] = lv.y; lcv[m][2] = lv.z; lcv[m][3] = lv.w;
    }
    if ((unsigned)(colBase - rowBase) < 128u)  // tile touches the diagonal
      epilogue<PASS, true>(acc, lcv, colBase, rowBase, wid, g, l15, lr, thrp, nthrn,
                           pminA, nmaxA, ap, hp, an, hn);
    else
      epilogue<PASS, false>(acc, lcv, colBase, rowBase, wid, g, l15, lr, thrp, nthrn,
                            pminA, nmaxA, ap, hp, an, hn);
    asm volatile("s_waitcnt vmcnt(0)");  // next-tile DMA landed (covered by compute)
    __syncthreads();
    cur ^= 1;
  }

  // block-end combine: butterfly across the 4 g-groups, then one atomic set
#pragma unroll
  for (int n = 0; n < 2; ++n) {
    const int grow = rowBase + wid * 32 + n * 16 + l15;
    if (PASS == 1) {
      float pmin = pminA[n], nmax = nmaxA[n];
      pmin = fminf(pmin, __shfl_xor(pmin, 16));
      pmin = fminf(pmin, __shfl_xor(pmin, 32));
      nmax = fmaxf(nmax, __shfl_xor(nmax, 16));
      nmax = fmaxf(nmax, __shfl_xor(nmax, 32));
      if (g == 0 && pmin < INFINITY) atomicMin(&pminu[grow], f2u_mono(pmin));
      if (g == 1 && nmax > -INFINITY) atomicMax(&nmaxu[grow], f2u_mono(nmax));
    } else {
      float a0 = ap[n], a1 = hp[n], a2 = an[n], a3 = hn[n];
      a0 += __shfl_xor(a0, 16); a0 += __shfl_xor(a0, 32);
      a1 += __shfl_xor(a1, 16); a1 += __shfl_xor(a1, 32);
      a2 += __shfl_xor(a2, 16); a2 += __shfl_xor(a2, 32);
      a3 += __shfl_xor(a3, 16); a3 += __shfl_xor(a3, 32);
      float v = (g == 0) ? a0 : (g == 1) ? a1 : (g == 2) ? a2 : a3;
      if (v > 0.f) atomicAdd(sums + g * NROW + grow, v);
    }
  }
}

__global__ __launch_bounds__(256) void k_final(const float* __restrict__ sums,
                                               float* __restrict__ out) {
  const int t = threadIdx.x;
  float acc = 0.f, cnt = 0.f;
  for (int i = t; i < NROW; i += 256) {
    float ap = sums[i], hp = sums[NROW + i], an = sums[2 * NROW + i], hn = sums[3 * NROW + i];
    bool valid = (ap > 0.f) && (an > 0.f);
    float ps = (hp > 0.f) ? hp : ap;
    float ns = (hn > 0.f) ? hn : an;
    float loss = 0.5f * log1pf(ps) + 0.02f * log1pf(ns);
    if (valid) { acc += loss; cnt += 1.f; }
  }
#pragma unroll
  for (int o = 32; o > 0; o >>= 1) {
    acc += __shfl_down(acc, o);
    cnt += __shfl_down(cnt, o);
  }
  __shared__ float sa[4], sc[4];
  int w = t >> 6, lane = t & 63;
  if (lane == 0) { sa[w] = acc; sc[w] = cnt; }
  __syncthreads();
  if (t == 0) {
    float A = sa[0] + sa[1] + sa[2] + sa[3];
    float C = sc[0] + sc[1] + sc[2] + sc[3];
    out[0] = A / fmaxf(C, 1.f);
  }
}

extern "C" void kernel_launch(void* const* d_in, const int* in_sizes, int n_in,
                              void* d_out, int out_size, void* d_ws, size_t ws_size,
                              hipStream_t stream) {
  const float* emb = (const float*)d_in[0];
  const int* labels = (const int*)d_in[1];
  float* out = (float*)d_out;

  // ws layout: [bf16 emb: 2MB][pminu:32K][nmaxu:32K][sums: 4x32K]
  unsigned short* embh = (unsigned short*)d_ws;
  unsigned* pminu = (unsigned*)((char*)d_ws + (size_t)NROW * NDIM * 2);
  unsigned* nmaxu = pminu + NROW;
  float* sums = (float*)(nmaxu + NROW);

  hipMemsetAsync(pminu, 0xFF, (size_t)NROW * 4, stream);   // mapped +inf sentinel
  hipMemsetAsync(nmaxu, 0, (size_t)NROW * 4 * 5, stream);  // nmaxu + 4 sums = 0

  k_convert<<<NROW * NDIM / (256 * 8), 256, 0, stream>>>(emb, embh);
  dim3 grid(NROW / (CTILE * CCHUNK), 64);
  k_sim<1><<<grid, 256, 0, stream>>>(embh, labels, pminu, nmaxu, sums);
  k_sim<2><<<grid, 256, 0, stream>>>(embh, labels, pminu, nmaxu, sums);
  k_final<<<1, 256, 0, stream>>>(sums, out);
}